// Round 10
// baseline (236.343 us; speedup 1.0000x reference)
//
#include <hip/hip_runtime.h>
#include <stdint.h>

#define NB 8
#define NN 1024
#define LOG2E 1.44269504088896f

typedef short short8 __attribute__((ext_vector_type(8)));
typedef float floatx4 __attribute__((ext_vector_type(4)));

static __device__ __forceinline__ short f2bf(float x) {   // round-nearest-even
    union { float f; uint32_t u; } v; v.f = x;
    uint32_t r = (v.u + 0x7fffu + ((v.u >> 16) & 1u)) >> 16;
    return (short)r;
}

// ---------------- prep: adjacency bitmask + weight cvt + gsum zero ----------
__global__ __launch_bounds__(256) void prep_all(const int* __restrict__ adj,
        uint64_t* __restrict__ am,
        const float* __restrict__ w1, const float* __restrict__ w2,
        const float* __restrict__ w3, const float* __restrict__ wn,
        ushort* __restrict__ wb1, ushort* __restrict__ wb2,
        ushort* __restrict__ wb3, ushort* __restrict__ wnb,
        float* __restrict__ gsum) {
    if (blockIdx.x < 2048) {
        int wave = blockIdx.x * 4 + (threadIdx.x >> 6);
        int lane = threadIdx.x & 63;
        int b = wave >> 10;
        int i = wave & 1023;
        const int* row = adj + ((size_t)b * NN + i) * NN;
        uint64_t* outp = am + ((size_t)b * NN + i) * 16;
        for (int it = 0; it < 16; ++it) {
            int j = it * 64 + lane;
            int v = (row[j] > 0) || (j == i);
            uint64_t m = __ballot(v);
            if (lane == 0) outp[it] = m;
        }
        return;
    }
    int idx = (blockIdx.x - 2048) * 256 + threadIdx.x;
    const float* src; ushort* dst; int li;
    if (idx < 4096)        { src = w1; dst = wb1; li = idx; }
    else if (idx < 20480)  { src = w2; dst = wb2; li = idx - 4096; }
    else if (idx < 24576)  { src = w3; dst = wb3; li = idx - 20480; }
    else if (idx < 25600)  { src = wn; dst = wnb; li = idx - 24576; }
    else if (idx < 25728) {
        ((float4*)gsum)[idx - 25600] = make_float4(0.f, 0.f, 0.f, 0.f);
        return;
    } else return;
    float4 v = ((const float4*)src)[li];
    ushort4 o;
    o.x = (ushort)f2bf(v.x); o.y = (ushort)f2bf(v.y);
    o.z = (ushort)f2bf(v.z); o.w = (ushort)f2bf(v.w);
    ((ushort4*)dst)[li] = o;
}

// ---------------- MFMA GEMM: H = X @ W^T, fused s/d epilogue ----------------
// Output written in MFMA-B-FRAGMENT order: hbF[(b,hd)][jc][ks][ct][lane][u].
template<int K, bool CVT>
__global__ __launch_bounds__(256, 4) void gemm_mfma(const void* __restrict__ Xv,
        const ushort* __restrict__ Wt, ushort* __restrict__ hbF,
        const float* __restrict__ asrc, const float* __restrict__ adst,
        float* __restrict__ s_t, float* __restrict__ d_t, int nheads) {
    __shared__ ushort smem[2][64][88];
    int m0 = blockIdx.x * 64, n0 = blockIdx.y * 64;
    int hd = blockIdx.y;
    int tid = threadIdx.x, w = tid >> 6, L = tid & 63;
    int m15 = L & 15, kq = L >> 4;
    floatx4 acc[4];
#pragma unroll
    for (int ct = 0; ct < 4; ++ct) acc[ct] = (floatx4){0.f, 0.f, 0.f, 0.f};

    for (int k0 = 0; k0 < K; k0 += 64) {
#pragma unroll
        for (int it = 0; it < 2; ++it) {
            int idx = tid + it * 256;
            int r = idx >> 3, sg = idx & 7;
            if (CVT) {
                const float* xf = (const float*)Xv + (size_t)(m0 + r) * K + k0 + sg * 8;
                float4 a0 = *(const float4*)xf, a1 = *(const float4*)(xf + 4);
                ushort t8[8];
                t8[0] = (ushort)f2bf(a0.x); t8[1] = (ushort)f2bf(a0.y);
                t8[2] = (ushort)f2bf(a0.z); t8[3] = (ushort)f2bf(a0.w);
                t8[4] = (ushort)f2bf(a1.x); t8[5] = (ushort)f2bf(a1.y);
                t8[6] = (ushort)f2bf(a1.z); t8[7] = (ushort)f2bf(a1.w);
                *(uint4*)&smem[0][r][sg * 8] = *(uint4*)&t8[0];
            } else {
                const ushort* xs = (const ushort*)Xv + (size_t)(m0 + r) * K + k0 + sg * 8;
                *(uint4*)&smem[0][r][sg * 8] = *(const uint4*)xs;
            }
            *(uint4*)&smem[1][r][sg * 8] = *(const uint4*)&Wt[(size_t)(n0 + r) * K + k0 + sg * 8];
        }
        __syncthreads();
#pragma unroll
        for (int ks = 0; ks < 2; ++ks) {
            short8 a = *(const short8*)&smem[0][16 * w + m15][ks * 32 + kq * 8];
#pragma unroll
            for (int ct = 0; ct < 4; ++ct) {
                short8 bfr = *(const short8*)&smem[1][ct * 16 + m15][ks * 32 + kq * 8];
                acc[ct] = __builtin_amdgcn_mfma_f32_16x16x32_bf16(a, bfr, acc[ct], 0, 0, 0);
            }
        }
        __syncthreads();
    }

    // ---- fused s/d epilogue ----
    float asv[4], adv[4];
#pragma unroll
    for (int ct = 0; ct < 4; ++ct) {
        asv[ct] = asrc[hd * 64 + ct * 16 + m15];
        adv[ct] = adst[hd * 64 + ct * 16 + m15];
    }
#pragma unroll
    for (int r = 0; r < 4; ++r) {
        float sp = acc[0][r] * asv[0] + acc[1][r] * asv[1] + acc[2][r] * asv[2] + acc[3][r] * asv[3];
        float dp = acc[0][r] * adv[0] + acc[1][r] * adv[1] + acc[2][r] * adv[2] + acc[3][r] * adv[3];
#pragma unroll
        for (int off = 1; off < 16; off <<= 1) {
            sp += __shfl_xor(sp, off);
            dp += __shfl_xor(dp, off);
        }
        if (m15 == 0) {
            int mg = m0 + 16 * w + kq * 4 + r;
            int bb = mg >> 10, node = mg & 1023;
            s_t[((size_t)(bb * nheads + hd)) * NN + node] = sp;
            d_t[((size_t)(bb * nheads + hd)) * NN + node] = dp;
        }
    }

    // ---- rearrange to B-fragment order via LDS, then coalesced 8KB store ----
    ushort* tb = (ushort*)smem;    // 4096 ushorts: (ks*4+ct)*512 + Lf*8 + u
    int jj0 = 16 * w + kq * 4;
    int ks0 = jj0 >> 5, l4 = (jj0 >> 3) & 3, u0 = jj0 & 7;
#pragma unroll
    for (int ct = 0; ct < 4; ++ct) {
        ushort p4[4];
#pragma unroll
        for (int r = 0; r < 4; ++r) p4[r] = (ushort)f2bf(acc[ct][r]);
        *(ushort4*)&tb[(ks0 * 4 + ct) * 512 + (l4 * 16 + m15) * 8 + u0] = *(ushort4*)&p4[0];
    }
    __syncthreads();
    int bb = m0 >> 10, node0 = m0 & 1023, jc = node0 >> 6;
    size_t dstb = ((size_t)(bb * nheads + hd) * 16 + jc) * 4096;
#pragma unroll
    for (int e = 0; e < 2; ++e) {
        int idx = tid + e * 256;
        *(uint4*)&hbF[dstb + (size_t)idx * 8] = *(const uint4*)&tb[idx * 8];
    }
}

// ---------------- MFMA masked-softmax aggregation: register B-frags ----------
// UNITS sequential 16-row i-tiles per block, same (b,hd): the B-fragment
// addresses are i-tile-independent, so unit 2 re-reads unit 1's cache lines
// (halves cold slice traffic) at zero extra VGPR; s-stage + block-max
// amortized. bounds (256,4): 4 blocks/CU, single generation, no tail.
template<int UNITS>
__global__ __launch_bounds__(256, 4) void gat_agg_mfma(
        const ushort* __restrict__ hbF, const uint64_t* __restrict__ am,
        const float* __restrict__ s_t, const float* __restrict__ d_t,
        const float* __restrict__ bias, ushort* __restrict__ Xb,
        float* __restrict__ gsum, int nheads, int do_colsum) {
    __shared__ __align__(16) float s_lds[NN];     // 4 KB
    __shared__ float red4[4];
    __shared__ __align__(16) float fb[4][17][68]; // partials + denom row

    int hd = blockIdx.y;
    int b  = blockIdx.z;
    int HC = nheads * 64;
    int tid = threadIdx.x, w = tid >> 6, L = tid & 63;
    int m15 = L & 15, kq = L >> 4;

    // stage s + global max (once per block, shared by all units)
    const float* srow = s_t + ((size_t)b * nheads + hd) * NN;
    float4 s4 = ((const float4*)srow)[tid];
    *(float4*)&s_lds[tid * 4] = s4;
    float lm = fmaxf(fmaxf(s4.x, s4.y), fmaxf(s4.z, s4.w));
#pragma unroll
    for (int off = 32; off; off >>= 1) lm = fmaxf(lm, __shfl_xor(lm, off));
    if (L == 0) red4[w] = lm;
    __syncthreads();
    float smax = fmaxf(fmaxf(red4[0], red4[1]), fmaxf(red4[2], red4[3]));

    const ushort* hs = hbF + (size_t)(b * nheads + hd) * 16 * 4096;
    int wq = w * 4;

#pragma unroll 1
    for (int un = 0; un < UNITS; ++un) {
        int i0 = (blockIdx.x * UNITS + un) * 16;

        // per-unit adjacency + d_i
        const uint64_t* amrow = am + ((size_t)b * NN + i0 + m15) * 16 + w * 4;
        uint64_t aw[4];
        *(uint4*)&aw[0] = *(const uint4*)&amrow[0];
        *(uint4*)&aw[2] = *(const uint4*)&amrow[2];
        float d_i = d_t[((size_t)b * nheads + hd) * NN + i0 + m15];
        float t0 = smax + d_i;
        float m_up = fmaxf(t0, 0.2f * t0);   // exp-safe upper bound
        float m2n = -m_up * LOG2E;

        floatx4 acc[4];
#pragma unroll
        for (int ct = 0; ct < 4; ++ct) acc[ct] = (floatx4){0.f, 0.f, 0.f, 0.f};
        float lsum = 0.f;

        uint4 fr[2][4];
#define LOADG(dst, g) { int t_ = (g) >> 1, ks_ = (g) & 1;                          \
    const ushort* bp = hs + ((size_t)((wq + t_) * 8 + ks_ * 4)) * 512 + (size_t)L * 8; \
    dst[0] = *(const uint4*)bp;            dst[1] = *(const uint4*)(bp + 512);     \
    dst[2] = *(const uint4*)(bp + 1024);   dst[3] = *(const uint4*)(bp + 1536); }

        LOADG(fr[0], 0);
#pragma unroll
        for (int g = 0; g < 8; ++g) {
            if (g < 7) LOADG(fr[(g + 1) & 1], g + 1);
            int t = g >> 1, ks = g & 1;
            int jb = (wq + t) * 64 + ks * 32 + kq * 8;
            float sv[8];
            *(float4*)&sv[0] = *(const float4*)&s_lds[jb];
            *(float4*)&sv[4] = *(const float4*)&s_lds[jb + 4];
            unsigned byte = (unsigned)((aw[t] >> (ks * 32 + kq * 8)) & 0xffull);
            unsigned ue[8];
#pragma unroll
            for (int u = 0; u < 8; ++u) {
                float sc = sv[u] + d_i;
                float lk = fmaxf(sc, 0.2f * sc);
#if __has_builtin(__builtin_amdgcn_exp2f)
                float arg = __builtin_fmaf(lk, LOG2E, m2n);
                arg = ((byte >> u) & 1u) ? arg : -1e30f;
                float e = __builtin_amdgcn_exp2f(arg);
#else
                float e = __expf(fminf(lk + m2n, 0.f));
                e = ((byte >> u) & 1u) ? e : 0.f;
#endif
                lsum += e;
                ue[u] = __float_as_uint(e);
            }
            unsigned pk[4];
#pragma unroll
            for (int k2 = 0; k2 < 4; ++k2)
#if __has_builtin(__builtin_amdgcn_perm)
                pk[k2] = __builtin_amdgcn_perm(ue[2 * k2 + 1], ue[2 * k2], 0x07060302u);
#else
                pk[k2] = (ue[2 * k2] >> 16) | (ue[2 * k2 + 1] & 0xffff0000u);
#endif
            short8 afrag;
            *(uint4*)&afrag = *(uint4*)&pk[0];
#pragma unroll
            for (int ct = 0; ct < 4; ++ct) {
                short8 bfr;
                *(uint4*)&bfr = fr[g & 1][ct];
                acc[ct] = __builtin_amdgcn_mfma_f32_16x16x32_bf16(afrag, bfr, acc[ct], 0, 0, 0);
            }
        }
#undef LOADG

        // partial denom for row m15 over this wave's j-quarter
        lsum += __shfl_xor(lsum, 16);
        lsum += __shfl_xor(lsum, 32);

        // publish partials
#pragma unroll
        for (int ct = 0; ct < 4; ++ct)
#pragma unroll
            for (int r = 0; r < 4; ++r)
                fb[w][kq * 4 + r][ct * 16 + m15] = acc[ct][r];
        if (kq == 0) fb[w][16][m15] = lsum;
        __syncthreads();

        // combine 4 waves' partials; epilogue relu(acc/l + bias) -> bf16
        int rr = tid >> 4, c0 = (tid & 15) * 4;
        float s0 = 0.f, s1 = 0.f, s2 = 0.f, s3 = 0.f, ltot = 0.f;
#pragma unroll
        for (int w2 = 0; w2 < 4; ++w2) {
            float4 a4 = *(const float4*)&fb[w2][rr][c0];
            s0 += a4.x; s1 += a4.y; s2 += a4.z; s3 += a4.w;
            ltot += fb[w2][16][rr];
        }
        float li = 1.f / ltot;
        float4 bv = *(const float4*)&bias[hd * 64 + c0];
        float v0 = fmaxf(s0 * li + bv.x, 0.f);
        float v1 = fmaxf(s1 * li + bv.y, 0.f);
        float v2 = fmaxf(s2 * li + bv.z, 0.f);
        float v3 = fmaxf(s3 * li + bv.w, 0.f);
        ushort4 o;
        o.x = (ushort)f2bf(v0); o.y = (ushort)f2bf(v1);
        o.z = (ushort)f2bf(v2); o.w = (ushort)f2bf(v3);
        *(ushort4*)&Xb[((size_t)(b * NN + i0 + rr)) * HC + hd * 64 + c0] = o;

        if (do_colsum) {
            __syncthreads();
            *(float4*)&fb[0][rr][c0] = make_float4(v0, v1, v2, v3);
            __syncthreads();
            if (tid < 64) {
                float s = 0.f;
#pragma unroll
                for (int r2 = 0; r2 < 16; ++r2) s += fb[0][r2][tid];
                atomicAdd(&gsum[b * 64 + tid], s);
            }
        }
        if (un + 1 < UNITS) __syncthreads();   // fb reuse guard
    }
}

// ---------------- fused readout: gc + relu(X@wn.T+bn)·wv + gc ----------------
__global__ __launch_bounds__(256) void readout_fused(
        const ushort* __restrict__ xb, const ushort* __restrict__ wnb,
        const float* __restrict__ bn, const float* __restrict__ wg,
        const float* __restrict__ bg, const float* __restrict__ wv,
        const float* __restrict__ bv, const float* __restrict__ gsum,
        float* __restrict__ outp) {
    __shared__ ushort xs[64][88];
    __shared__ ushort wns[64][88];
    __shared__ float gcs;
    int b = blockIdx.y, n0 = blockIdx.x * 64;
    int tid = threadIdx.x, w = tid >> 6, L = tid & 63;
    int m15 = L & 15, kq = L >> 4;
#pragma unroll
    for (int it = 0; it < 2; ++it) {
        int idx = tid + it * 256;
        int r = idx >> 3, sg = idx & 7;
        *(uint4*)&xs[r][sg * 8]  = *(const uint4*)&xb[(size_t)(b * NN + n0 + r) * 64 + sg * 8];
        *(uint4*)&wns[r][sg * 8] = *(const uint4*)&wnb[r * 64 + sg * 8];
    }
    if (tid < 64) {
        float acc = bg[tid];
#pragma unroll 8
        for (int c = 0; c < 64; ++c) acc += gsum[b * 64 + c] * wg[tid * 64 + c];
        acc = fmaxf(acc, 0.f) * wv[64 + tid];
#pragma unroll
        for (int off = 32; off; off >>= 1) acc += __shfl_down(acc, off);
        if (tid == 0) gcs = acc + bv[0];
    }
    __syncthreads();

    floatx4 acc[4];
#pragma unroll
    for (int ct = 0; ct < 4; ++ct) acc[ct] = (floatx4){0.f, 0.f, 0.f, 0.f};
#pragma unroll
    for (int ks = 0; ks < 2; ++ks) {
        short8 a = *(const short8*)&xs[16 * w + m15][ks * 32 + kq * 8];
#pragma unroll
        for (int ct = 0; ct < 4; ++ct) {
            short8 bfr = *(const short8*)&wns[ct * 16 + m15][ks * 32 + kq * 8];
            acc[ct] = __builtin_amdgcn_mfma_f32_16x16x32_bf16(a, bfr, acc[ct], 0, 0, 0);
        }
    }
    float bnv[4], wvv[4];
#pragma unroll
    for (int ct = 0; ct < 4; ++ct) {
        bnv[ct] = bn[ct * 16 + m15];
        wvv[ct] = wv[ct * 16 + m15];
    }
    float gc = gcs;
#pragma unroll
    for (int r = 0; r < 4; ++r) {
        float rp = 0.f;
#pragma unroll
        for (int ct = 0; ct < 4; ++ct)
            rp += fmaxf(acc[ct][r] + bnv[ct], 0.f) * wvv[ct];
#pragma unroll
        for (int off = 1; off < 16; off <<= 1) rp += __shfl_xor(rp, off);
        if (m15 == 0)
            outp[(size_t)b * NN + n0 + 16 * w + kq * 4 + r] = rp + gc;
    }
}

extern "C" void kernel_launch(void* const* d_in, const int* in_sizes, int n_in,
                              void* d_out, int out_size, void* d_ws, size_t ws_size,
                              hipStream_t stream) {
    const float* x0  = (const float*)d_in[0];
    const int*   adj = (const int*)  d_in[1];
    const float* w1  = (const float*)d_in[2];
    const float* as1 = (const float*)d_in[3];
    const float* ad1 = (const float*)d_in[4];
    const float* b1  = (const float*)d_in[5];
    const float* w2  = (const float*)d_in[6];
    const float* as2 = (const float*)d_in[7];
    const float* ad2 = (const float*)d_in[8];
    const float* b2  = (const float*)d_in[9];
    const float* w3  = (const float*)d_in[10];
    const float* as3 = (const float*)d_in[11];
    const float* ad3 = (const float*)d_in[12];
    const float* b3  = (const float*)d_in[13];
    const float* wn  = (const float*)d_in[14];
    const float* bn  = (const float*)d_in[15];
    const float* wg  = (const float*)d_in[16];
    const float* bg  = (const float*)d_in[17];
    const float* wv  = (const float*)d_in[18];
    const float* bv  = (const float*)d_in[19];
    float* outp = (float*)d_out;

    char* wsb = (char*)d_ws;
    uint64_t* amask = (uint64_t*)(wsb);                      // 1 MB
    ushort* hbF  = (ushort*)(wsb + (1u  << 20));             // 4 MB (frag order)
    ushort* xbA  = (ushort*)(wsb + (5u  << 20));             // 4 MB
    ushort* xbB  = (ushort*)(wsb + (9u  << 20));             // 4 MB
    char* tail   = wsb + (14u << 20);
    float* s_buf = (float*)(tail);                           // 128 KB
    float* d_buf = (float*)(tail + (1u << 17));              // 128 KB
    ushort* wb1  = (ushort*)(tail + (2u << 17));             // 32 KB
    ushort* wb2  = (ushort*)(tail + (2u << 17) + (1u << 15));// 128 KB
    ushort* wb3  = (ushort*)(tail + (2u << 17) + (5u << 15));// 32 KB
    ushort* wnb  = (ushort*)(tail + (2u << 17) + (6u << 15));// 8 KB
    float* gsum  = (float*) (tail + (2u << 17) + (6u << 15) + (1u << 13));

    prep_all<<<2149, 256, 0, stream>>>(adj, amask, w1, w2, w3, wn,
                                       wb1, wb2, wb3, wnb, gsum);

    // layer 1 (K=64, H=4; x0 converted in-staging)
    gemm_mfma<64, true><<<dim3(128, 4), 256, 0, stream>>>(x0, wb1, hbF, as1, ad1, s_buf, d_buf, 4);
    gat_agg_mfma<2><<<dim3(32, 4, 8), 256, 0, stream>>>(hbF, amask, s_buf, d_buf, b1, xbA, gsum, 4, 0);

    // layer 2 (K=256, H=4)
    gemm_mfma<256, false><<<dim3(128, 4), 256, 0, stream>>>(xbA, wb2, hbF, as2, ad2, s_buf, d_buf, 4);
    gat_agg_mfma<2><<<dim3(32, 4, 8), 256, 0, stream>>>(hbF, amask, s_buf, d_buf, b2, xbB, gsum, 4, 0);

    // layer 3 (K=256, H=1) + fused column-sum
    gemm_mfma<256, false><<<dim3(128, 1), 256, 0, stream>>>(xbB, wb3, hbF, as3, ad3, s_buf, d_buf, 1);
    gat_agg_mfma<1><<<dim3(64, 1, 8), 256, 0, stream>>>(hbF, amask, s_buf, d_buf, b3, xbA, gsum, 1, 1);

    // fused readout
    readout_fused<<<dim3(16, 8), 256, 0, stream>>>(xbA, wnb, bn, wg, bg, wv, bv, gsum, outp);
}

// Round 11
// 172.658 us; speedup vs baseline: 1.3689x; 1.3689x over previous
//
#include <hip/hip_runtime.h>
#include <stdint.h>

#define NB 8
#define NN 1024
#define LOG2E 1.44269504088896f

typedef short short8 __attribute__((ext_vector_type(8)));
typedef float floatx4 __attribute__((ext_vector_type(4)));

static __device__ __forceinline__ short f2bf(float x) {   // round-nearest-even
    union { float f; uint32_t u; } v; v.f = x;
    uint32_t r = (v.u + 0x7fffu + ((v.u >> 16) & 1u)) >> 16;
    return (short)r;
}

// ---------------- prep: adjacency bitmask + weight cvt + gsum zero ----------
// adjacency blocks XCD-swizzled: b = vb&7 so amask[b] is built on XCD b.
__global__ __launch_bounds__(256) void prep_all(const int* __restrict__ adj,
        uint64_t* __restrict__ am,
        const float* __restrict__ w1, const float* __restrict__ w2,
        const float* __restrict__ w3, const float* __restrict__ wn,
        ushort* __restrict__ wb1, ushort* __restrict__ wb2,
        ushort* __restrict__ wb3, ushort* __restrict__ wnb,
        float* __restrict__ gsum) {
    if (blockIdx.x < 2048) {
        int vb = blockIdx.x;
        int b = vb & 7;
        int i = (vb >> 3) * 4 + (threadIdx.x >> 6);
        int lane = threadIdx.x & 63;
        const int* row = adj + ((size_t)b * NN + i) * NN;
        uint64_t* outp = am + ((size_t)b * NN + i) * 16;
        for (int it = 0; it < 16; ++it) {
            int j = it * 64 + lane;
            int v = (row[j] > 0) || (j == i);
            uint64_t m = __ballot(v);
            if (lane == 0) outp[it] = m;
        }
        return;
    }
    int idx = (blockIdx.x - 2048) * 256 + threadIdx.x;
    const float* src; ushort* dst; int li;
    if (idx < 4096)        { src = w1; dst = wb1; li = idx; }
    else if (idx < 20480)  { src = w2; dst = wb2; li = idx - 4096; }
    else if (idx < 24576)  { src = w3; dst = wb3; li = idx - 20480; }
    else if (idx < 25600)  { src = wn; dst = wnb; li = idx - 24576; }
    else if (idx < 25728) {
        ((float4*)gsum)[idx - 25600] = make_float4(0.f, 0.f, 0.f, 0.f);
        return;
    } else return;
    float4 v = ((const float4*)src)[li];
    ushort4 o;
    o.x = (ushort)f2bf(v.x); o.y = (ushort)f2bf(v.y);
    o.z = (ushort)f2bf(v.z); o.w = (ushort)f2bf(v.w);
    ((ushort4*)dst)[li] = o;
}

// ---------------- MFMA GEMM: H = X @ W^T, fused s/d epilogue ----------------
// Output in MFMA-B-FRAGMENT order: hbF[(b,hd)][jc][ks][ct][lane][u].
// 1D grid 128*nheads, XCD swizzle: batch b = vb&7 runs on XCD b, so the
// hbF/xb/s/d lines it writes are L2-warm for the agg on the same XCD.
template<int K, bool CVT>
__global__ __launch_bounds__(256, 4) void gemm_mfma(const void* __restrict__ Xv,
        const ushort* __restrict__ Wt, ushort* __restrict__ hbF,
        const float* __restrict__ asrc, const float* __restrict__ adst,
        float* __restrict__ s_t, float* __restrict__ d_t, int nheads) {
    __shared__ ushort smem[2][64][88];
    int vb = blockIdx.x;
    int bsw = vb & 7;
    int rest = vb >> 3;
    int hd = rest >> 4;                  // 16 m-tiles per (b,hd)
    int mt = bsw * 16 + (rest & 15);
    int m0 = mt * 64, n0 = hd * 64;
    int tid = threadIdx.x, w = tid >> 6, L = tid & 63;
    int m15 = L & 15, kq = L >> 4;
    floatx4 acc[4];
#pragma unroll
    for (int ct = 0; ct < 4; ++ct) acc[ct] = (floatx4){0.f, 0.f, 0.f, 0.f};

    for (int k0 = 0; k0 < K; k0 += 64) {
#pragma unroll
        for (int it = 0; it < 2; ++it) {
            int idx = tid + it * 256;
            int r = idx >> 3, sg = idx & 7;
            if (CVT) {
                const float* xf = (const float*)Xv + (size_t)(m0 + r) * K + k0 + sg * 8;
                float4 a0 = *(const float4*)xf, a1 = *(const float4*)(xf + 4);
                ushort t8[8];
                t8[0] = (ushort)f2bf(a0.x); t8[1] = (ushort)f2bf(a0.y);
                t8[2] = (ushort)f2bf(a0.z); t8[3] = (ushort)f2bf(a0.w);
                t8[4] = (ushort)f2bf(a1.x); t8[5] = (ushort)f2bf(a1.y);
                t8[6] = (ushort)f2bf(a1.z); t8[7] = (ushort)f2bf(a1.w);
                *(uint4*)&smem[0][r][sg * 8] = *(uint4*)&t8[0];
            } else {
                const ushort* xs = (const ushort*)Xv + (size_t)(m0 + r) * K + k0 + sg * 8;
                *(uint4*)&smem[0][r][sg * 8] = *(const uint4*)xs;
            }
            *(uint4*)&smem[1][r][sg * 8] = *(const uint4*)&Wt[(size_t)(n0 + r) * K + k0 + sg * 8];
        }
        __syncthreads();
#pragma unroll
        for (int ks = 0; ks < 2; ++ks) {
            short8 a = *(const short8*)&smem[0][16 * w + m15][ks * 32 + kq * 8];
#pragma unroll
            for (int ct = 0; ct < 4; ++ct) {
                short8 bfr = *(const short8*)&smem[1][ct * 16 + m15][ks * 32 + kq * 8];
                acc[ct] = __builtin_amdgcn_mfma_f32_16x16x32_bf16(a, bfr, acc[ct], 0, 0, 0);
            }
        }
        __syncthreads();
    }

    // ---- fused s/d epilogue ----
    float asv[4], adv[4];
#pragma unroll
    for (int ct = 0; ct < 4; ++ct) {
        asv[ct] = asrc[hd * 64 + ct * 16 + m15];
        adv[ct] = adst[hd * 64 + ct * 16 + m15];
    }
#pragma unroll
    for (int r = 0; r < 4; ++r) {
        float sp = acc[0][r] * asv[0] + acc[1][r] * asv[1] + acc[2][r] * asv[2] + acc[3][r] * asv[3];
        float dp = acc[0][r] * adv[0] + acc[1][r] * adv[1] + acc[2][r] * adv[2] + acc[3][r] * adv[3];
#pragma unroll
        for (int off = 1; off < 16; off <<= 1) {
            sp += __shfl_xor(sp, off);
            dp += __shfl_xor(dp, off);
        }
        if (m15 == 0) {
            int mg = m0 + 16 * w + kq * 4 + r;
            int bb = mg >> 10, node = mg & 1023;
            s_t[((size_t)(bb * nheads + hd)) * NN + node] = sp;
            d_t[((size_t)(bb * nheads + hd)) * NN + node] = dp;
        }
    }

    // ---- rearrange to B-fragment order via LDS, then coalesced 8KB store ----
    ushort* tb = (ushort*)smem;    // 4096 ushorts: (ks*4+ct)*512 + Lf*8 + u
    int jj0 = 16 * w + kq * 4;
    int ks0 = jj0 >> 5, l4 = (jj0 >> 3) & 3, u0 = jj0 & 7;
#pragma unroll
    for (int ct = 0; ct < 4; ++ct) {
        ushort p4[4];
#pragma unroll
        for (int r = 0; r < 4; ++r) p4[r] = (ushort)f2bf(acc[ct][r]);
        *(ushort4*)&tb[(ks0 * 4 + ct) * 512 + (l4 * 16 + m15) * 8 + u0] = *(ushort4*)&p4[0];
    }
    __syncthreads();
    int bb = m0 >> 10, node0 = m0 & 1023, jc = node0 >> 6;
    size_t dstb = ((size_t)(bb * nheads + hd) * 16 + jc) * 4096;
#pragma unroll
    for (int e = 0; e < 2; ++e) {
        int idx = tid + e * 256;
        *(uint4*)&hbF[dstb + (size_t)idx * 8] = *(const uint4*)&tb[idx * 8];
    }
}

// ---------------- MFMA masked-softmax aggregation: register B-frags ----------
// 1D grid 512*nheads, XCD swizzle: b = vb&7 (same XCD that produced the
// slice), hd = rest>>6 so concurrent blocks on an XCD share 1-2 slices
// (256 KB, L2-resident). Frags load with one coalesced dwordx4/lane,
// double-buffered in registers; zero barriers in the j-loop.
__global__ __launch_bounds__(256, 4) void gat_agg_mfma(
        const ushort* __restrict__ hbF, const uint64_t* __restrict__ am,
        const float* __restrict__ s_t, const float* __restrict__ d_t,
        const float* __restrict__ bias, ushort* __restrict__ Xb,
        float* __restrict__ gsum, int nheads, int do_colsum) {
    __shared__ __align__(16) float s_lds[NN];     // 4 KB
    __shared__ float red4[4];
    __shared__ __align__(16) float fb[4][17][68]; // partials + denom row

    int vb = blockIdx.x;
    int b = vb & 7;
    int rest = vb >> 3;
    int hd = rest >> 6;
    int i0 = (rest & 63) * 16;
    int HC = nheads * 64;
    int tid = threadIdx.x, w = tid >> 6, L = tid & 63;
    int m15 = L & 15, kq = L >> 4;

    // stage s + global max
    const float* srow = s_t + ((size_t)b * nheads + hd) * NN;
    float4 s4 = ((const float4*)srow)[tid];
    *(float4*)&s_lds[tid * 4] = s4;
    float lm = fmaxf(fmaxf(s4.x, s4.y), fmaxf(s4.z, s4.w));
#pragma unroll
    for (int off = 32; off; off >>= 1) lm = fmaxf(lm, __shfl_xor(lm, off));
    if (L == 0) red4[w] = lm;

    // per-lane adjacency words (row i0+m15, chunks w*4..w*4+3) + d_i
    const uint64_t* amrow = am + ((size_t)b * NN + i0 + m15) * 16 + w * 4;
    uint64_t aw[4];
    *(uint4*)&aw[0] = *(const uint4*)&amrow[0];
    *(uint4*)&aw[2] = *(const uint4*)&amrow[2];
    float d_i = d_t[((size_t)b * nheads + hd) * NN + i0 + m15];
    __syncthreads();

    float smax = fmaxf(fmaxf(red4[0], red4[1]), fmaxf(red4[2], red4[3]));
    float t0 = smax + d_i;
    float m_up = fmaxf(t0, 0.2f * t0);   // exp-safe upper bound (leaky monotone)
    float m2n = -m_up * LOG2E;

    floatx4 acc[4];
#pragma unroll
    for (int ct = 0; ct < 4; ++ct) acc[ct] = (floatx4){0.f, 0.f, 0.f, 0.f};
    float lsum = 0.f;

    const ushort* hs = hbF + (size_t)(b * nheads + hd) * 16 * 4096;
    int wq = w * 4;

    uint4 fr[2][4];
#define LOADG(dst, g) { int t_ = (g) >> 1, ks_ = (g) & 1;                          \
    const ushort* bp = hs + ((size_t)((wq + t_) * 8 + ks_ * 4)) * 512 + (size_t)L * 8; \
    dst[0] = *(const uint4*)bp;            dst[1] = *(const uint4*)(bp + 512);     \
    dst[2] = *(const uint4*)(bp + 1024);   dst[3] = *(const uint4*)(bp + 1536); }

    LOADG(fr[0], 0);
#pragma unroll
    for (int g = 0; g < 8; ++g) {
        if (g < 7) LOADG(fr[(g + 1) & 1], g + 1);
        int t = g >> 1, ks = g & 1;
        int jb = (wq + t) * 64 + ks * 32 + kq * 8;
        float sv[8];
        *(float4*)&sv[0] = *(const float4*)&s_lds[jb];
        *(float4*)&sv[4] = *(const float4*)&s_lds[jb + 4];
        unsigned byte = (unsigned)((aw[t] >> (ks * 32 + kq * 8)) & 0xffull);
        unsigned ue[8];
#pragma unroll
        for (int u = 0; u < 8; ++u) {
            float sc = sv[u] + d_i;
            float lk = fmaxf(sc, 0.2f * sc);
#if __has_builtin(__builtin_amdgcn_exp2f)
            float arg = __builtin_fmaf(lk, LOG2E, m2n);
            arg = ((byte >> u) & 1u) ? arg : -1e30f;
            float e = __builtin_amdgcn_exp2f(arg);
#else
            float e = __expf(fminf(lk + m2n, 0.f));
            e = ((byte >> u) & 1u) ? e : 0.f;
#endif
            lsum += e;
            ue[u] = __float_as_uint(e);
        }
        unsigned pk[4];
#pragma unroll
        for (int k2 = 0; k2 < 4; ++k2)
#if __has_builtin(__builtin_amdgcn_perm)
            pk[k2] = __builtin_amdgcn_perm(ue[2 * k2 + 1], ue[2 * k2], 0x07060302u);
#else
            pk[k2] = (ue[2 * k2] >> 16) | (ue[2 * k2 + 1] & 0xffff0000u);
#endif
        short8 afrag;
        *(uint4*)&afrag = *(uint4*)&pk[0];
#pragma unroll
        for (int ct = 0; ct < 4; ++ct) {
            short8 bfr;
            *(uint4*)&bfr = fr[g & 1][ct];
            acc[ct] = __builtin_amdgcn_mfma_f32_16x16x32_bf16(afrag, bfr, acc[ct], 0, 0, 0);
        }
    }
#undef LOADG

    // partial denom for row m15 over this wave's j-quarter
    lsum += __shfl_xor(lsum, 16);
    lsum += __shfl_xor(lsum, 32);

    // publish partials
#pragma unroll
    for (int ct = 0; ct < 4; ++ct)
#pragma unroll
        for (int r = 0; r < 4; ++r)
            fb[w][kq * 4 + r][ct * 16 + m15] = acc[ct][r];
    if (kq == 0) fb[w][16][m15] = lsum;
    __syncthreads();

    // combine 4 waves' partials; epilogue relu(acc/l + bias) -> bf16
    int rr = tid >> 4, c0 = (tid & 15) * 4;
    float s0 = 0.f, s1 = 0.f, s2 = 0.f, s3 = 0.f, ltot = 0.f;
#pragma unroll
    for (int w2 = 0; w2 < 4; ++w2) {
        float4 a4 = *(const float4*)&fb[w2][rr][c0];
        s0 += a4.x; s1 += a4.y; s2 += a4.z; s3 += a4.w;
        ltot += fb[w2][16][rr];
    }
    float li = 1.f / ltot;
    float4 bv = *(const float4*)&bias[hd * 64 + c0];
    float v0 = fmaxf(s0 * li + bv.x, 0.f);
    float v1 = fmaxf(s1 * li + bv.y, 0.f);
    float v2 = fmaxf(s2 * li + bv.z, 0.f);
    float v3 = fmaxf(s3 * li + bv.w, 0.f);
    ushort4 o;
    o.x = (ushort)f2bf(v0); o.y = (ushort)f2bf(v1);
    o.z = (ushort)f2bf(v2); o.w = (ushort)f2bf(v3);
    *(ushort4*)&Xb[((size_t)(b * NN + i0 + rr)) * HC + hd * 64 + c0] = o;

    if (do_colsum) {
        __syncthreads();
        *(float4*)&fb[0][rr][c0] = make_float4(v0, v1, v2, v3);
        __syncthreads();
        if (tid < 64) {
            float s = 0.f;
#pragma unroll
            for (int r2 = 0; r2 < 16; ++r2) s += fb[0][r2][tid];
            atomicAdd(&gsum[b * 64 + tid], s);
        }
    }
}

// ---------------- fused readout: gc + relu(X@wn.T+bn)·wv + gc ----------------
// 1D grid 128, XCD swizzle b = vb&7.
__global__ __launch_bounds__(256) void readout_fused(
        const ushort* __restrict__ xb, const ushort* __restrict__ wnb,
        const float* __restrict__ bn, const float* __restrict__ wg,
        const float* __restrict__ bg, const float* __restrict__ wv,
        const float* __restrict__ bv, const float* __restrict__ gsum,
        float* __restrict__ outp) {
    __shared__ ushort xs[64][88];
    __shared__ ushort wns[64][88];
    __shared__ float gcs;
    int vb = blockIdx.x;
    int b = vb & 7, n0 = (vb >> 3) * 64;
    int tid = threadIdx.x, w = tid >> 6, L = tid & 63;
    int m15 = L & 15, kq = L >> 4;
#pragma unroll
    for (int it = 0; it < 2; ++it) {
        int idx = tid + it * 256;
        int r = idx >> 3, sg = idx & 7;
        *(uint4*)&xs[r][sg * 8]  = *(const uint4*)&xb[(size_t)(b * NN + n0 + r) * 64 + sg * 8];
        *(uint4*)&wns[r][sg * 8] = *(const uint4*)&wnb[r * 64 + sg * 8];
    }
    if (tid < 64) {
        float acc = bg[tid];
#pragma unroll 8
        for (int c = 0; c < 64; ++c) acc += gsum[b * 64 + c] * wg[tid * 64 + c];
        acc = fmaxf(acc, 0.f) * wv[64 + tid];
#pragma unroll
        for (int off = 32; off; off >>= 1) acc += __shfl_down(acc, off);
        if (tid == 0) gcs = acc + bv[0];
    }
    __syncthreads();

    floatx4 acc[4];
#pragma unroll
    for (int ct = 0; ct < 4; ++ct) acc[ct] = (floatx4){0.f, 0.f, 0.f, 0.f};
#pragma unroll
    for (int ks = 0; ks < 2; ++ks) {
        short8 a = *(const short8*)&xs[16 * w + m15][ks * 32 + kq * 8];
#pragma unroll
        for (int ct = 0; ct < 4; ++ct) {
            short8 bfr = *(const short8*)&wns[ct * 16 + m15][ks * 32 + kq * 8];
            acc[ct] = __builtin_amdgcn_mfma_f32_16x16x32_bf16(a, bfr, acc[ct], 0, 0, 0);
        }
    }
    float bnv[4], wvv[4];
#pragma unroll
    for (int ct = 0; ct < 4; ++ct) {
        bnv[ct] = bn[ct * 16 + m15];
        wvv[ct] = wv[ct * 16 + m15];
    }
    float gc = gcs;
#pragma unroll
    for (int r = 0; r < 4; ++r) {
        float rp = 0.f;
#pragma unroll
        for (int ct = 0; ct < 4; ++ct)
            rp += fmaxf(acc[ct][r] + bnv[ct], 0.f) * wvv[ct];
#pragma unroll
        for (int off = 1; off < 16; off <<= 1) rp += __shfl_xor(rp, off);
        if (m15 == 0)
            outp[(size_t)b * NN + n0 + 16 * w + kq * 4 + r] = rp + gc;
    }
}

extern "C" void kernel_launch(void* const* d_in, const int* in_sizes, int n_in,
                              void* d_out, int out_size, void* d_ws, size_t ws_size,
                              hipStream_t stream) {
    const float* x0  = (const float*)d_in[0];
    const int*   adj = (const int*)  d_in[1];
    const float* w1  = (const float*)d_in[2];
    const float* as1 = (const float*)d_in[3];
    const float* ad1 = (const float*)d_in[4];
    const float* b1  = (const float*)d_in[5];
    const float* w2  = (const float*)d_in[6];
    const float* as2 = (const float*)d_in[7];
    const float* ad2 = (const float*)d_in[8];
    const float* b2  = (const float*)d_in[9];
    const float* w3  = (const float*)d_in[10];
    const float* as3 = (const float*)d_in[11];
    const float* ad3 = (const float*)d_in[12];
    const float* b3  = (const float*)d_in[13];
    const float* wn  = (const float*)d_in[14];
    const float* bn  = (const float*)d_in[15];
    const float* wg  = (const float*)d_in[16];
    const float* bg  = (const float*)d_in[17];
    const float* wv  = (const float*)d_in[18];
    const float* bv  = (const float*)d_in[19];
    float* outp = (float*)d_out;

    char* wsb = (char*)d_ws;
    uint64_t* amask = (uint64_t*)(wsb);                      // 1 MB
    ushort* hbF  = (ushort*)(wsb + (1u  << 20));             // 4 MB (frag order)
    ushort* xbA  = (ushort*)(wsb + (5u  << 20));             // 4 MB
    ushort* xbB  = (ushort*)(wsb + (9u  << 20));             // 4 MB
    char* tail   = wsb + (14u << 20);
    float* s_buf = (float*)(tail);                           // 128 KB
    float* d_buf = (float*)(tail + (1u << 17));              // 128 KB
    ushort* wb1  = (ushort*)(tail + (2u << 17));             // 32 KB
    ushort* wb2  = (ushort*)(tail + (2u << 17) + (1u << 15));// 128 KB
    ushort* wb3  = (ushort*)(tail + (2u << 17) + (5u << 15));// 32 KB
    ushort* wnb  = (ushort*)(tail + (2u << 17) + (6u << 15));// 8 KB
    float* gsum  = (float*) (tail + (2u << 17) + (6u << 15) + (1u << 13));

    prep_all<<<2149, 256, 0, stream>>>(adj, amask, w1, w2, w3, wn,
                                       wb1, wb2, wb3, wnb, gsum);

    // layer 1 (K=64, H=4; x0 converted in-staging)
    gemm_mfma<64, true><<<512, 256, 0, stream>>>(x0, wb1, hbF, as1, ad1, s_buf, d_buf, 4);
    gat_agg_mfma<<<2048, 256, 0, stream>>>(hbF, amask, s_buf, d_buf, b1, xbA, gsum, 4, 0);

    // layer 2 (K=256, H=4)
    gemm_mfma<256, false><<<512, 256, 0, stream>>>(xbA, wb2, hbF, as2, ad2, s_buf, d_buf, 4);
    gat_agg_mfma<<<2048, 256, 0, stream>>>(hbF, amask, s_buf, d_buf, b2, xbB, gsum, 4, 0);

    // layer 3 (K=256, H=1) + fused column-sum
    gemm_mfma<256, false><<<128, 256, 0, stream>>>(xbB, wb3, hbF, as3, ad3, s_buf, d_buf, 1);
    gat_agg_mfma<<<512, 256, 0, stream>>>(hbF, amask, s_buf, d_buf, b3, xbA, gsum, 1, 1);

    // fused readout
    readout_fused<<<128, 256, 0, stream>>>(xbA, wnb, bn, wg, bg, wv, bv, gsum, outp);
}

// Round 14
// 172.559 us; speedup vs baseline: 1.3696x; 1.0006x over previous
//
#include <hip/hip_runtime.h>
#include <stdint.h>

#define NB 8
#define NN 1024
#define LOG2E 1.44269504088896f

typedef short short8 __attribute__((ext_vector_type(8)));
typedef float floatx4 __attribute__((ext_vector_type(4)));

static __device__ __forceinline__ short f2bf(float x) {   // round-nearest-even
    union { float f; uint32_t u; } v; v.f = x;
    uint32_t r = (v.u + 0x7fffu + ((v.u >> 16) & 1u)) >> 16;
    return (short)r;
}

// ---------------- prep: adjacency bitmask + weight cvt + gsum zero ----------
// adjacency blocks XCD-swizzled: b = vb&7 so amask[b] is built on XCD b.
__global__ __launch_bounds__(256) void prep_all(const int* __restrict__ adj,
        uint64_t* __restrict__ am,
        const float* __restrict__ w1, const float* __restrict__ w2,
        const float* __restrict__ w3, const float* __restrict__ wn,
        ushort* __restrict__ wb1, ushort* __restrict__ wb2,
        ushort* __restrict__ wb3, ushort* __restrict__ wnb,
        float* __restrict__ gsum) {
    if (blockIdx.x < 2048) {
        int vb = blockIdx.x;
        int b = vb & 7;
        int i = (vb >> 3) * 4 + (threadIdx.x >> 6);
        int lane = threadIdx.x & 63;
        const int* row = adj + ((size_t)b * NN + i) * NN;
        uint64_t* outp = am + ((size_t)b * NN + i) * 16;
        for (int it = 0; it < 16; ++it) {
            int j = it * 64 + lane;
            int v = (row[j] > 0) || (j == i);
            uint64_t m = __ballot(v);
            if (lane == 0) outp[it] = m;
        }
        return;
    }
    int idx = (blockIdx.x - 2048) * 256 + threadIdx.x;
    const float* src; ushort* dst; int li;
    if (idx < 4096)        { src = w1; dst = wb1; li = idx; }
    else if (idx < 20480)  { src = w2; dst = wb2; li = idx - 4096; }
    else if (idx < 24576)  { src = w3; dst = wb3; li = idx - 20480; }
    else if (idx < 25600)  { src = wn; dst = wnb; li = idx - 24576; }
    else if (idx < 25728) {
        ((float4*)gsum)[idx - 25600] = make_float4(0.f, 0.f, 0.f, 0.f);
        return;
    } else return;
    float4 v = ((const float4*)src)[li];
    ushort4 o;
    o.x = (ushort)f2bf(v.x); o.y = (ushort)f2bf(v.y);
    o.z = (ushort)f2bf(v.z); o.w = (ushort)f2bf(v.w);
    ((ushort4*)dst)[li] = o;
}

// ---------------- MFMA GEMM: H = X @ W^T, fused s/d epilogue ----------------
// Output in MFMA-B-FRAGMENT order: hbF[(b,hd)][jc][ks][ct][lane][u].
// 1D grid, XCD swizzle: batch b = vb&7 runs on XCD b, so the hbF/xb/s/d
// lines it writes are L2-warm for the agg on the same XCD.
template<int K, bool CVT>
__global__ __launch_bounds__(256, 4) void gemm_mfma(const void* __restrict__ Xv,
        const ushort* __restrict__ Wt, ushort* __restrict__ hbF,
        const float* __restrict__ asrc, const float* __restrict__ adst,
        float* __restrict__ s_t, float* __restrict__ d_t, int nheads) {
    __shared__ ushort smem[2][64][88];
    int vb = blockIdx.x;
    int bsw = vb & 7;
    int rest = vb >> 3;
    int hd = rest >> 4;                  // 16 m-tiles per (b,hd)
    int mt = bsw * 16 + (rest & 15);
    int m0 = mt * 64, n0 = hd * 64;
    int tid = threadIdx.x, w = tid >> 6, L = tid & 63;
    int m15 = L & 15, kq = L >> 4;
    floatx4 acc[4];
#pragma unroll
    for (int ct = 0; ct < 4; ++ct) acc[ct] = (floatx4){0.f, 0.f, 0.f, 0.f};

    for (int k0 = 0; k0 < K; k0 += 64) {
#pragma unroll
        for (int it = 0; it < 2; ++it) {
            int idx = tid + it * 256;
            int r = idx >> 3, sg = idx & 7;
            if (CVT) {
                const float* xf = (const float*)Xv + (size_t)(m0 + r) * K + k0 + sg * 8;
                float4 a0 = *(const float4*)xf, a1 = *(const float4*)(xf + 4);
                ushort t8[8];
                t8[0] = (ushort)f2bf(a0.x); t8[1] = (ushort)f2bf(a0.y);
                t8[2] = (ushort)f2bf(a0.z); t8[3] = (ushort)f2bf(a0.w);
                t8[4] = (ushort)f2bf(a1.x); t8[5] = (ushort)f2bf(a1.y);
                t8[6] = (ushort)f2bf(a1.z); t8[7] = (ushort)f2bf(a1.w);
                *(uint4*)&smem[0][r][sg * 8] = *(uint4*)&t8[0];
            } else {
                const ushort* xs = (const ushort*)Xv + (size_t)(m0 + r) * K + k0 + sg * 8;
                *(uint4*)&smem[0][r][sg * 8] = *(const uint4*)xs;
            }
            *(uint4*)&smem[1][r][sg * 8] = *(const uint4*)&Wt[(size_t)(n0 + r) * K + k0 + sg * 8];
        }
        __syncthreads();
#pragma unroll
        for (int ks = 0; ks < 2; ++ks) {
            short8 a = *(const short8*)&smem[0][16 * w + m15][ks * 32 + kq * 8];
#pragma unroll
            for (int ct = 0; ct < 4; ++ct) {
                short8 bfr = *(const short8*)&smem[1][ct * 16 + m15][ks * 32 + kq * 8];
                acc[ct] = __builtin_amdgcn_mfma_f32_16x16x32_bf16(a, bfr, acc[ct], 0, 0, 0);
            }
        }
        __syncthreads();
    }

    // ---- fused s/d epilogue ----
    float asv[4], adv[4];
#pragma unroll
    for (int ct = 0; ct < 4; ++ct) {
        asv[ct] = asrc[hd * 64 + ct * 16 + m15];
        adv[ct] = adst[hd * 64 + ct * 16 + m15];
    }
#pragma unroll
    for (int r = 0; r < 4; ++r) {
        float sp = acc[0][r] * asv[0] + acc[1][r] * asv[1] + acc[2][r] * asv[2] + acc[3][r] * asv[3];
        float dp = acc[0][r] * adv[0] + acc[1][r] * adv[1] + acc[2][r] * adv[2] + acc[3][r] * adv[3];
#pragma unroll
        for (int off = 1; off < 16; off <<= 1) {
            sp += __shfl_xor(sp, off);
            dp += __shfl_xor(dp, off);
        }
        if (m15 == 0) {
            int mg = m0 + 16 * w + kq * 4 + r;
            int bb = mg >> 10, node = mg & 1023;
            s_t[((size_t)(bb * nheads + hd)) * NN + node] = sp;
            d_t[((size_t)(bb * nheads + hd)) * NN + node] = dp;
        }
    }

    // ---- rearrange to B-fragment order via LDS, then coalesced 8KB store ----
    ushort* tb = (ushort*)smem;    // 4096 ushorts: (ks*4+ct)*512 + Lf*8 + u
    int jj0 = 16 * w + kq * 4;
    int ks0 = jj0 >> 5, l4 = (jj0 >> 3) & 3, u0 = jj0 & 7;
#pragma unroll
    for (int ct = 0; ct < 4; ++ct) {
        ushort p4[4];
#pragma unroll
        for (int r = 0; r < 4; ++r) p4[r] = (ushort)f2bf(acc[ct][r]);
        *(ushort4*)&tb[(ks0 * 4 + ct) * 512 + (l4 * 16 + m15) * 8 + u0] = *(ushort4*)&p4[0];
    }
    __syncthreads();
    int bb = m0 >> 10, node0 = m0 & 1023, jc = node0 >> 6;
    size_t dstb = ((size_t)(bb * nheads + hd) * 16 + jc) * 4096;
#pragma unroll
    for (int e = 0; e < 2; ++e) {
        int idx = tid + e * 256;
        *(uint4*)&hbF[dstb + (size_t)idx * 8] = *(const uint4*)&tb[idx * 8];
    }
}

// ---------------- MFMA masked-softmax aggregation: register B-frags ----------
// XCD swizzle: b = vb&7 (same XCD that produced the slice), hd = rest>>6 so
// concurrent blocks on an XCD share 1-2 slices (256 KB, L2-resident).
// Frags load with one coalesced dwordx4/lane, double-buffered in registers;
// zero barriers in the j-loop.
__global__ __launch_bounds__(256, 4) void gat_agg_mfma(
        const ushort* __restrict__ hbF, const uint64_t* __restrict__ am,
        const float* __restrict__ s_t, const float* __restrict__ d_t,
        const float* __restrict__ bias, ushort* __restrict__ Xb,
        float* __restrict__ gsum, int nheads, int do_colsum) {
    __shared__ __align__(16) float s_lds[NN];     // 4 KB
    __shared__ float red4[4];
    __shared__ __align__(16) float fb[4][17][68]; // partials + denom row

    int vb = blockIdx.x;
    int b = vb & 7;
    int rest = vb >> 3;
    int hd = rest >> 6;
    int i0 = (rest & 63) * 16;
    int HC = nheads * 64;
    int tid = threadIdx.x, w = tid >> 6, L = tid & 63;
    int m15 = L & 15, kq = L >> 4;

    // stage s + global max
    const float* srow = s_t + ((size_t)b * nheads + hd) * NN;
    float4 s4 = ((const float4*)srow)[tid];
    *(float4*)&s_lds[tid * 4] = s4;
    float lm = fmaxf(fmaxf(s4.x, s4.y), fmaxf(s4.z, s4.w));
#pragma unroll
    for (int off = 32; off; off >>= 1) lm = fmaxf(lm, __shfl_xor(lm, off));
    if (L == 0) red4[w] = lm;

    // per-lane adjacency words (row i0+m15, chunks w*4..w*4+3) + d_i
    const uint64_t* amrow = am + ((size_t)b * NN + i0 + m15) * 16 + w * 4;
    uint64_t aw[4];
    *(uint4*)&aw[0] = *(const uint4*)&amrow[0];
    *(uint4*)&aw[2] = *(const uint4*)&amrow[2];
    float d_i = d_t[((size_t)b * nheads + hd) * NN + i0 + m15];
    __syncthreads();

    float smax = fmaxf(fmaxf(red4[0], red4[1]), fmaxf(red4[2], red4[3]));
    float t0 = smax + d_i;
    float m_up = fmaxf(t0, 0.2f * t0);   // exp-safe upper bound (leaky monotone)
    float m2n = -m_up * LOG2E;

    floatx4 acc[4];
#pragma unroll
    for (int ct = 0; ct < 4; ++ct) acc[ct] = (floatx4){0.f, 0.f, 0.f, 0.f};
    float lsum = 0.f;

    const ushort* hs = hbF + (size_t)(b * nheads + hd) * 16 * 4096;
    int wq = w * 4;

    uint4 fr[2][4];
#define LOADG(dst, g) { int t_ = (g) >> 1, ks_ = (g) & 1;                          \
    const ushort* bp = hs + ((size_t)((wq + t_) * 8 + ks_ * 4)) * 512 + (size_t)L * 8; \
    dst[0] = *(const uint4*)bp;            dst[1] = *(const uint4*)(bp + 512);     \
    dst[2] = *(const uint4*)(bp + 1024);   dst[3] = *(const uint4*)(bp + 1536); }

    LOADG(fr[0], 0);
#pragma unroll
    for (int g = 0; g < 8; ++g) {
        if (g < 7) LOADG(fr[(g + 1) & 1], g + 1);
        int t = g >> 1, ks = g & 1;
        int jb = (wq + t) * 64 + ks * 32 + kq * 8;
        float sv[8];
        *(float4*)&sv[0] = *(const float4*)&s_lds[jb];
        *(float4*)&sv[4] = *(const float4*)&s_lds[jb + 4];
        unsigned byte = (unsigned)((aw[t] >> (ks * 32 + kq * 8)) & 0xffull);
        unsigned ue[8];
#pragma unroll
        for (int u = 0; u < 8; ++u) {
            float sc = sv[u] + d_i;
            float lk = fmaxf(sc, 0.2f * sc);
#if __has_builtin(__builtin_amdgcn_exp2f)
            float arg = __builtin_fmaf(lk, LOG2E, m2n);
            arg = ((byte >> u) & 1u) ? arg : -1e30f;
            float e = __builtin_amdgcn_exp2f(arg);
#else
            float e = __expf(fminf(lk + m2n, 0.f));
            e = ((byte >> u) & 1u) ? e : 0.f;
#endif
            lsum += e;
            ue[u] = __float_as_uint(e);
        }
        unsigned pk[4];
#pragma unroll
        for (int k2 = 0; k2 < 4; ++k2)
#if __has_builtin(__builtin_amdgcn_perm)
            pk[k2] = __builtin_amdgcn_perm(ue[2 * k2 + 1], ue[2 * k2], 0x07060302u);
#else
            pk[k2] = (ue[2 * k2] >> 16) | (ue[2 * k2 + 1] & 0xffff0000u);
#endif
        short8 afrag;
        *(uint4*)&afrag = *(uint4*)&pk[0];
#pragma unroll
        for (int ct = 0; ct < 4; ++ct) {
            short8 bfr;
            *(uint4*)&bfr = fr[g & 1][ct];
            acc[ct] = __builtin_amdgcn_mfma_f32_16x16x32_bf16(afrag, bfr, acc[ct], 0, 0, 0);
        }
    }
#undef LOADG

    // partial denom for row m15 over this wave's j-quarter
    lsum += __shfl_xor(lsum, 16);
    lsum += __shfl_xor(lsum, 32);

    // publish partials
#pragma unroll
    for (int ct = 0; ct < 4; ++ct)
#pragma unroll
        for (int r = 0; r < 4; ++r)
            fb[w][kq * 4 + r][ct * 16 + m15] = acc[ct][r];
    if (kq == 0) fb[w][16][m15] = lsum;
    __syncthreads();

    // combine 4 waves' partials; epilogue relu(acc/l + bias) -> bf16
    int rr = tid >> 4, c0 = (tid & 15) * 4;
    float s0 = 0.f, s1 = 0.f, s2 = 0.f, s3 = 0.f, ltot = 0.f;
#pragma unroll
    for (int w2 = 0; w2 < 4; ++w2) {
        float4 a4 = *(const float4*)&fb[w2][rr][c0];
        s0 += a4.x; s1 += a4.y; s2 += a4.z; s3 += a4.w;
        ltot += fb[w2][16][rr];
    }
    float li = 1.f / ltot;
    float4 bv = *(const float4*)&bias[hd * 64 + c0];
    float v0 = fmaxf(s0 * li + bv.x, 0.f);
    float v1 = fmaxf(s1 * li + bv.y, 0.f);
    float v2 = fmaxf(s2 * li + bv.z, 0.f);
    float v3 = fmaxf(s3 * li + bv.w, 0.f);
    ushort4 o;
    o.x = (ushort)f2bf(v0); o.y = (ushort)f2bf(v1);
    o.z = (ushort)f2bf(v2); o.w = (ushort)f2bf(v3);
    *(ushort4*)&Xb[((size_t)(b * NN + i0 + rr)) * HC + hd * 64 + c0] = o;

    if (do_colsum) {
        __syncthreads();
        *(float4*)&fb[0][rr][c0] = make_float4(v0, v1, v2, v3);
        __syncthreads();
        if (tid < 64) {
            float s = 0.f;
#pragma unroll
            for (int r2 = 0; r2 < 16; ++r2) s += fb[0][r2][tid];
            atomicAdd(&gsum[b * 64 + tid], s);
        }
    }
}

// ---------------- fused readout: gc + relu(X@wn.T+bn)·wv + gc ----------------
// 1D grid 128, XCD swizzle b = vb&7.
__global__ __launch_bounds__(256) void readout_fused(
        const ushort* __restrict__ xb, const ushort* __restrict__ wnb,
        const float* __restrict__ bn, const float* __restrict__ wg,
        const float* __restrict__ bg, const float* __restrict__ wv,
        const float* __restrict__ bv, const float* __restrict__ gsum,
        float* __restrict__ outp) {
    __shared__ ushort xs[64][88];
    __shared__ ushort wns[64][88];
    __shared__ float gcs;
    int vb = blockIdx.x;
    int b = vb & 7, n0 = (vb >> 3) * 64;
    int tid = threadIdx.x, w = tid >> 6, L = tid & 63;
    int m15 = L & 15, kq = L >> 4;
#pragma unroll
    for (int it = 0; it < 2; ++it) {
        int idx = tid + it * 256;
        int r = idx >> 3, sg = idx & 7;
        *(uint4*)&xs[r][sg * 8]  = *(const uint4*)&xb[(size_t)(b * NN + n0 + r) * 64 + sg * 8];
        *(uint4*)&wns[r][sg * 8] = *(const uint4*)&wnb[r * 64 + sg * 8];
    }
    if (tid < 64) {
        float acc = bg[tid];
#pragma unroll 8
        for (int c = 0; c < 64; ++c) acc += gsum[b * 64 + c] * wg[tid * 64 + c];
        acc = fmaxf(acc, 0.f) * wv[64 + tid];
#pragma unroll
        for (int off = 32; off; off >>= 1) acc += __shfl_down(acc, off);
        if (tid == 0) gcs = acc + bv[0];
    }
    __syncthreads();

    floatx4 acc[4];
#pragma unroll
    for (int ct = 0; ct < 4; ++ct) acc[ct] = (floatx4){0.f, 0.f, 0.f, 0.f};
#pragma unroll
    for (int ks = 0; ks < 2; ++ks) {
        short8 a = *(const short8*)&xs[16 * w + m15][ks * 32 + kq * 8];
#pragma unroll
        for (int ct = 0; ct < 4; ++ct) {
            short8 bfr = *(const short8*)&wns[ct * 16 + m15][ks * 32 + kq * 8];
            acc[ct] = __builtin_amdgcn_mfma_f32_16x16x32_bf16(a, bfr, acc[ct], 0, 0, 0);
        }
    }
    float bnv[4], wvv[4];
#pragma unroll
    for (int ct = 0; ct < 4; ++ct) {
        bnv[ct] = bn[ct * 16 + m15];
        wvv[ct] = wv[ct * 16 + m15];
    }
    float gc = gcs;
#pragma unroll
    for (int r = 0; r < 4; ++r) {
        float rp = 0.f;
#pragma unroll
        for (int ct = 0; ct < 4; ++ct)
            rp += fmaxf(acc[ct][r] + bnv[ct], 0.f) * wvv[ct];
#pragma unroll
        for (int off = 1; off < 16; off <<= 1) rp += __shfl_xor(rp, off);
        if (m15 == 0)
            outp[(size_t)b * NN + n0 + 16 * w + kq * 4 + r] = rp + gc;
    }
}

extern "C" void kernel_launch(void* const* d_in, const int* in_sizes, int n_in,
                              void* d_out, int out_size, void* d_ws, size_t ws_size,
                              hipStream_t stream) {
    const float* x0  = (const float*)d_in[0];
    const int*   adj = (const int*)  d_in[1];
    const float* w1  = (const float*)d_in[2];
    const float* as1 = (const float*)d_in[3];
    const float* ad1 = (const float*)d_in[4];
    const float* b1  = (const float*)d_in[5];
    const float* w2  = (const float*)d_in[6];
    const float* as2 = (const float*)d_in[7];
    const float* ad2 = (const float*)d_in[8];
    const float* b2  = (const float*)d_in[9];
    const float* w3  = (const float*)d_in[10];
    const float* as3 = (const float*)d_in[11];
    const float* ad3 = (const float*)d_in[12];
    const float* b3  = (const float*)d_in[13];
    const float* wn  = (const float*)d_in[14];
    const float* bn  = (const float*)d_in[15];
    const float* wg  = (const float*)d_in[16];
    const float* bg  = (const float*)d_in[17];
    const float* wv  = (const float*)d_in[18];
    const float* bv  = (const float*)d_in[19];
    float* outp = (float*)d_out;

    char* wsb = (char*)d_ws;
    uint64_t* amask = (uint64_t*)(wsb);                      // 1 MB
    ushort* hbF  = (ushort*)(wsb + (1u  << 20));             // 4 MB (frag order)
    ushort* xbA  = (ushort*)(wsb + (5u  << 20));             // 4 MB
    ushort* xbB  = (ushort*)(wsb + (9u  << 20));             // 4 MB
    char* tail   = wsb + (14u << 20);
    float* s_buf = (float*)(tail);                           // 128 KB
    float* d_buf = (float*)(tail + (1u << 17));              // 128 KB
    ushort* wb1  = (ushort*)(tail + (2u << 17));             // 32 KB
    ushort* wb2  = (ushort*)(tail + (2u << 17) + (1u << 15));// 128 KB
    ushort* wb3  = (ushort*)(tail + (2u << 17) + (5u << 15));// 32 KB
    ushort* wnb  = (ushort*)(tail + (2u << 17) + (6u << 15));// 8 KB
    float* gsum  = (float*) (tail + (2u << 17) + (6u << 15) + (1u << 13));

    prep_all<<<2149, 256, 0, stream>>>(adj, amask, w1, w2, w3, wn,
                                       wb1, wb2, wb3, wnb, gsum);

    // layer 1 (K=64, H=4; x0 converted in-staging)
    gemm_mfma<64, true><<<512, 256, 0, stream>>>(x0, wb1, hbF, as1, ad1, s_buf, d_buf, 4);
    gat_agg_mfma<<<2048, 256, 0, stream>>>(hbF, amask, s_buf, d_buf, b1, xbA, gsum, 4, 0);

    // layer 2 (K=256, H=4)
    gemm_mfma<256, false><<<512, 256, 0, stream>>>(xbA, wb2, hbF, as2, ad2, s_buf, d_buf, 4);
    gat_agg_mfma<<<2048, 256, 0, stream>>>(hbF, amask, s_buf, d_buf, b2, xbB, gsum, 4, 0);

    // layer 3 (K=256, H=1) + fused column-sum
    gemm_mfma<256, false><<<128, 256, 0, stream>>>(xbB, wb3, hbF, as3, ad3, s_buf, d_buf, 1);
    gat_agg_mfma<<<512, 256, 0, stream>>>(hbF, amask, s_buf, d_buf, b3, xbA, gsum, 1, 1);

    // fused readout
    readout_fused<<<128, 256, 0, stream>>>(xbA, wnb, bn, wg, bg, wv, bv, gsum, outp);
}